// Round 1
// baseline (962.213 us; speedup 1.0000x reference)
//
#include <hip/hip_runtime.h>
#include <hip/hip_bf16.h>
#include <math.h>

#define M_SLOTS 8192
#define N_DIM   4096
#define FVS     64
#define PLEN    64
#define CDIM    256
#define NIN     512
#define NOUT    512
#define STEPS   8
#define EPS_F   1e-8f

// ---------------- helpers ----------------

__device__ inline float wave_sum(float v) {
    for (int off = 32; off; off >>= 1) v += __shfl_down(v, off);
    return v;
}

// block(1024) sum: all threads receive the result. sh must have >=17 floats.
__device__ inline float blk_sum_1024(float v, float* sh) {
    v = wave_sum(v);
    int lane = threadIdx.x & 63, wid = threadIdx.x >> 6;
    if (lane == 0) sh[wid] = v;
    __syncthreads();
    if (threadIdx.x < 16) {
        v = sh[threadIdx.x];
        for (int off = 8; off; off >>= 1) v += __shfl_down(v, off);
        if (threadIdx.x == 0) sh[16] = v;
    }
    __syncthreads();
    float r = sh[16];
    __syncthreads();
    return r;
}

__device__ inline float blk_max_1024(float v, float* sh) {
    for (int off = 32; off; off >>= 1) v = fmaxf(v, __shfl_down(v, off));
    int lane = threadIdx.x & 63, wid = threadIdx.x >> 6;
    if (lane == 0) sh[wid] = v;
    __syncthreads();
    if (threadIdx.x < 16) {
        v = sh[threadIdx.x];
        for (int off = 8; off; off >>= 1) v = fmaxf(v, __shfl_down(v, off));
        if (threadIdx.x == 0) sh[16] = v;
    }
    __syncthreads();
    float r = sh[16];
    __syncthreads();
    return r;
}

// ---------------- kernels ----------------

// X = x @ input_embedding   (1x512 @ 512x64 -> 64)
__global__ void k_init_X(const float* __restrict__ x, const float* __restrict__ emb,
                         float* __restrict__ X) {
    int j = threadIdx.x;  // 64 threads
    float acc = 0.f;
    for (int i = 0; i < NIN; ++i) acc += x[i] * emb[i * FVS + j];
    X[j] = acc;
}

// c = sigmoid(Wc @ concat(X, prog_t) + bc)   (256 outputs, dot-128)
__global__ void k_controller(const float* __restrict__ X, const float* __restrict__ prog_t,
                             const float* __restrict__ Wc, const float* __restrict__ bc,
                             float* __restrict__ c) {
    __shared__ float in[FVS + PLEN];
    int tid = threadIdx.x;  // 256 threads
    if (tid < FVS) in[tid] = X[tid];
    else if (tid < FVS + PLEN) in[tid] = prog_t[tid - FVS];
    __syncthreads();
    float acc = bc[tid];
    const float* wrow = Wc + tid * (FVS + PLEN);
    #pragma unroll 8
    for (int i = 0; i < FVS + PLEN; ++i) acc += wrow[i] * in[i];
    c[tid] = 1.f / (1.f + expf(-acc));
}

// k = tanh(Wk@c+bk), e = sigmoid(We@c+be), a = tanh(Wa@c+ba), kr = tanh(Wrk@prog+brk)
// one wave per output row; 4*4096 = 16384 waves -> 4096 blocks of 256
__global__ void k_keys(const float* __restrict__ c, const float* __restrict__ prog_t,
                       const float* __restrict__ Wk, const float* __restrict__ bk,
                       const float* __restrict__ We, const float* __restrict__ be,
                       const float* __restrict__ Wa, const float* __restrict__ ba,
                       const float* __restrict__ Wrk, const float* __restrict__ brk,
                       float* __restrict__ k, float* __restrict__ e,
                       float* __restrict__ a, float* __restrict__ kr) {
    int gw   = (blockIdx.x * blockDim.x + threadIdx.x) >> 6;  // global wave id
    int lane = threadIdx.x & 63;
    int mat  = gw >> 12;      // / 4096
    int row  = gw & 4095;
    float acc = 0.f;
    if (mat == 0) {
        const float* W = Wk + row * CDIM;
        #pragma unroll
        for (int i = lane; i < CDIM; i += 64) acc += W[i] * c[i];
    } else if (mat == 1) {
        const float* W = We + row * CDIM;
        #pragma unroll
        for (int i = lane; i < CDIM; i += 64) acc += W[i] * c[i];
    } else if (mat == 2) {
        const float* W = Wa + row * CDIM;
        #pragma unroll
        for (int i = lane; i < CDIM; i += 64) acc += W[i] * c[i];
    } else {
        acc = Wrk[row * PLEN + lane] * prog_t[lane];
    }
    acc = wave_sum(acc);
    if (lane == 0) {
        if (mat == 0)      k[row]  = tanhf(acc + bk[row]);
        else if (mat == 1) e[row]  = 1.f / (1.f + expf(-(acc + be[row])));
        else if (mat == 2) a[row]  = tanhf(acc + ba[row]);
        else               kr[row] = tanhf(acc + brk[row]);
    }
}

// per-row: sim[m] = mem[m].key ; norm2[m] = |mem[m]|^2   (one block per row)
__global__ void k_sim(const float* __restrict__ mem, const float* __restrict__ key,
                      float* __restrict__ sim, float* __restrict__ norm2) {
    int m = blockIdx.x;
    const float4* row = (const float4*)(mem + (size_t)m * N_DIM);
    const float4* k4  = (const float4*)key;
    float s = 0.f, n = 0.f;
    #pragma unroll 4
    for (int i = threadIdx.x; i < N_DIM / 4; i += 256) {
        float4 v = row[i], kk = k4[i];
        s += v.x * kk.x + v.y * kk.y + v.z * kk.z + v.w * kk.w;
        n += v.x * v.x + v.y * v.y + v.z * v.z + v.w * v.w;
    }
    s = wave_sum(s); n = wave_sum(n);
    __shared__ float sh[4][2];
    int wid = threadIdx.x >> 6, lane = threadIdx.x & 63;
    if (lane == 0) { sh[wid][0] = s; sh[wid][1] = n; }
    __syncthreads();
    if (threadIdx.x == 0) {
        sim[m]   = sh[0][0] + sh[1][0] + sh[2][0] + sh[3][0];
        norm2[m] = sh[0][1] + sh[1][1] + sh[2][1] + sh[3][1];
    }
}

// w = softmax(sim / (sqrt(norm2)*|key| + eps))   single block of 1024
__global__ void k_softmax(const float* __restrict__ key, const float* __restrict__ sim,
                          const float* __restrict__ norm2, float* __restrict__ w) {
    __shared__ float sh[17];
    int tid = threadIdx.x;
    float kn = 0.f;
    for (int i = tid; i < N_DIM; i += 1024) { float v = key[i]; kn += v * v; }
    kn = blk_sum_1024(kn, sh);
    float knorm = sqrtf(kn);

    float vals[M_SLOTS / 1024];
    float mx = -INFINITY;
    #pragma unroll
    for (int j = 0; j < M_SLOTS / 1024; ++j) {
        int m = tid + j * 1024;
        float v = sim[m] / (sqrtf(norm2[m]) * knorm + EPS_F);
        vals[j] = v;
        mx = fmaxf(mx, v);
    }
    mx = blk_max_1024(mx, sh);
    float lsum = 0.f;
    #pragma unroll
    for (int j = 0; j < M_SLOTS / 1024; ++j) {
        vals[j] = expf(vals[j] - mx);
        lsum += vals[j];
    }
    lsum = blk_sum_1024(lsum, sh);
    float inv = 1.f / lsum;
    #pragma unroll
    for (int j = 0; j < M_SLOTS / 1024; ++j) w[tid + j * 1024] = vals[j] * inv;
}

// mem_dst[m] = mem_src[m]*(1-ww[m]*e) + ww[m]*a ; fused re-sim with kr + new rownorm
__global__ void k_update(const float* __restrict__ src, float* __restrict__ dst,
                         const float* __restrict__ w, const float* __restrict__ e,
                         const float* __restrict__ a, const float* __restrict__ kr,
                         float* __restrict__ sim, float* __restrict__ norm2) {
    int m = blockIdx.x;
    float ww = w[m];
    const float4* s4 = (const float4*)(src + (size_t)m * N_DIM);
    float4*       d4 = (float4*)(dst + (size_t)m * N_DIM);
    const float4* e4 = (const float4*)e;
    const float4* a4 = (const float4*)a;
    const float4* r4 = (const float4*)kr;
    float s = 0.f, n = 0.f;
    #pragma unroll 4
    for (int i = threadIdx.x; i < N_DIM / 4; i += 256) {
        float4 v = s4[i], ee = e4[i], aa = a4[i], kk = r4[i];
        float4 nv;
        nv.x = v.x * (1.f - ww * ee.x) + ww * aa.x;
        nv.y = v.y * (1.f - ww * ee.y) + ww * aa.y;
        nv.z = v.z * (1.f - ww * ee.z) + ww * aa.z;
        nv.w = v.w * (1.f - ww * ee.w) + ww * aa.w;
        d4[i] = nv;
        s += nv.x * kk.x + nv.y * kk.y + nv.z * kk.z + nv.w * kk.w;
        n += nv.x * nv.x + nv.y * nv.y + nv.z * nv.z + nv.w * nv.w;
    }
    s = wave_sum(s); n = wave_sum(n);
    __shared__ float sh[4][2];
    int wid = threadIdx.x >> 6, lane = threadIdx.x & 63;
    if (lane == 0) { sh[wid][0] = s; sh[wid][1] = n; }
    __syncthreads();
    if (threadIdx.x == 0) {
        sim[m]   = sh[0][0] + sh[1][0] + sh[2][0] + sh[3][0];
        norm2[m] = sh[0][1] + sh[1][1] + sh[2][1] + sh[3][1];
    }
}

// partial[rc][:] = sum over 64 rows of w[r]*mem[r][:]   grid (4, 128), 256 thr
__global__ void k_read(const float* __restrict__ mem, const float* __restrict__ w,
                       float* __restrict__ partial) {
    int c4 = blockIdx.x * 256 + threadIdx.x;  // float4 column index [0,1024)
    int rc = blockIdx.y;                      // row chunk [0,128)
    int r0 = rc * 64;
    const float4* m4 = (const float4*)mem;
    float4 acc = make_float4(0.f, 0.f, 0.f, 0.f);
    for (int r = r0; r < r0 + 64; ++r) {
        float ww = w[r];
        float4 v = m4[(size_t)r * (N_DIM / 4) + c4];
        acc.x += ww * v.x; acc.y += ww * v.y; acc.z += ww * v.z; acc.w += ww * v.w;
    }
    ((float4*)partial)[(size_t)rc * (N_DIM / 4) + c4] = acc;
}

// red[c] = sum_j partial[j][c]   (16 blocks x 256)
__global__ void k_read_reduce(const float* __restrict__ partial, float* __restrict__ red) {
    int cidx = blockIdx.x * 256 + threadIdx.x;
    float acc = 0.f;
    #pragma unroll 8
    for (int j = 0; j < 128; ++j) acc += partial[j * N_DIM + cidx];
    red[cidx] = acc;
}

// X = tanh(X @ red.reshape(64,64))   one block of 64
__global__ void k_exec(float* __restrict__ X, const float* __restrict__ red) {
    __shared__ float xs[FVS];
    int j = threadIdx.x;
    xs[j] = X[j];
    __syncthreads();
    float acc = 0.f;
    #pragma unroll
    for (int i = 0; i < FVS; ++i) acc += xs[i] * red[i * FVS + j];
    X[j] = tanhf(acc);
}

// out = X @ output_embedding   (1x64 @ 64x512)
__global__ void k_out(const float* __restrict__ X, const float* __restrict__ emb,
                      float* __restrict__ out) {
    __shared__ float xs[FVS];
    int tid = threadIdx.x;  // 512 threads
    if (tid < FVS) xs[tid] = X[tid];
    __syncthreads();
    float acc = 0.f;
    #pragma unroll
    for (int i = 0; i < FVS; ++i) acc += xs[i] * emb[i * NOUT + tid];
    out[tid] = acc;
}

// ---------------- launch ----------------

extern "C" void kernel_launch(void* const* d_in, const int* in_sizes, int n_in,
                              void* d_out, int out_size, void* d_ws, size_t ws_size,
                              hipStream_t stream) {
    const float* x        = (const float*)d_in[0];
    const float* program  = (const float*)d_in[1];
    const float* memory0  = (const float*)d_in[2];
    const float* in_emb   = (const float*)d_in[3];
    const float* out_emb  = (const float*)d_in[4];
    const float* Wc       = (const float*)d_in[5];
    const float* bc       = (const float*)d_in[6];
    const float* Wk       = (const float*)d_in[7];
    const float* bk       = (const float*)d_in[8];
    const float* We       = (const float*)d_in[9];
    const float* be       = (const float*)d_in[10];
    const float* Wa       = (const float*)d_in[11];
    const float* ba       = (const float*)d_in[12];
    const float* Wrk      = (const float*)d_in[13];
    const float* brk      = (const float*)d_in[14];
    float* out = (float*)d_out;

    float* wsmem   = (float*)d_ws;                 // [M_SLOTS * N_DIM]
    float* X       = wsmem + (size_t)M_SLOTS * N_DIM;
    float* c       = X + FVS;
    float* k       = c + CDIM;
    float* e       = k + N_DIM;
    float* a       = e + N_DIM;
    float* kr      = a + N_DIM;
    float* sim     = kr + N_DIM;
    float* norm2   = sim + M_SLOTS;
    float* w       = norm2 + M_SLOTS;
    float* red     = w + M_SLOTS;
    float* partial = red + N_DIM;                  // [128 * N_DIM]

    k_init_X<<<1, FVS, 0, stream>>>(x, in_emb, X);

    for (int t = 0; t < STEPS; ++t) {
        const float* prog_t = program + t * PLEN;
        const float* src    = (t == 0) ? memory0 : wsmem;

        k_controller<<<1, CDIM, 0, stream>>>(X, prog_t, Wc, bc, c);
        k_keys<<<4096, 256, 0, stream>>>(c, prog_t, Wk, bk, We, be, Wa, ba, Wrk, brk,
                                         k, e, a, kr);
        k_sim<<<M_SLOTS, 256, 0, stream>>>(src, k, sim, norm2);
        k_softmax<<<1, 1024, 0, stream>>>(k, sim, norm2, w);
        k_update<<<M_SLOTS, 256, 0, stream>>>(src, wsmem, w, e, a, kr, sim, norm2);
        k_softmax<<<1, 1024, 0, stream>>>(kr, sim, norm2, w);
        k_read<<<dim3(4, 128), 256, 0, stream>>>(wsmem, w, partial);
        k_read_reduce<<<16, 256, 0, stream>>>(partial, red);
        k_exec<<<1, FVS, 0, stream>>>(X, red);
    }

    k_out<<<1, NOUT, 0, stream>>>(X, out_emb, out);
}